// Round 16
// baseline (62.499 us; speedup 1.0000x reference)
//
#include <hip/hip_runtime.h>
#include <hip/hip_bf16.h>
#include <cstdint>
#include <cstddef>

typedef __attribute__((ext_vector_type(8))) short bf16x8;
typedef __attribute__((ext_vector_type(4))) float f32x4;

__device__ __forceinline__ unsigned short f2bf(float f) {
  union { float f; unsigned u; } v; v.f = f;
  unsigned r = v.u + 0x7FFFu + ((v.u >> 16) & 1u);
  return (unsigned short)(r >> 16);
}

__device__ __forceinline__ float bf2f(unsigned short h) {
  union { float f; unsigned u; } c; c.u = ((unsigned)h) << 16;
  return c.f;
}

__device__ __forceinline__ void gload_lds16(const void* g, void* l) {
  __builtin_amdgcn_global_load_lds(
      (const __attribute__((address_space(1))) unsigned int*)g,
      (__attribute__((address_space(3))) unsigned int*)l, 16, 0, 0);
}

// ---------------------------------------------------------------------------
// K01: R15-identical. Launched TWICE this round as a duration probe (pure
// function of x,W -> idempotent; delta vs R15 total = k01 duration).
// ---------------------------------------------------------------------------
__global__ __launch_bounds__(1024) void k01_prep(const float* __restrict__ W,
                                                 unsigned short* __restrict__ Wt,
                                                 const float* __restrict__ x,
                                                 unsigned short* __restrict__ xbf,
                                                 float* __restrict__ rnorm,
                                                 float* __restrict__ sp) {
  __shared__ __align__(16) char sm[82176];
  int tid = threadIdx.x;
  int b = blockIdx.x;
  int lane = tid & 63;
  int wid = tid >> 6;  // 0..15

  int k0 = (b & 15) * 64;
  int c0 = (b >> 4) * 64;
  int tx = tid & 63;
  int ty = tid >> 6;
  float wreg[4];
#pragma unroll
  for (int i = 0; i < 4; ++i) {
    int c = c0 + tx;
    wreg[i] = (c < 1000) ? W[(size_t)(k0 + i * 16 + ty) * 1000 + c] : 0.f;
  }

  {
    float (*sblk)[1024] = (float(*)[1024])sm;
    int row0 = b * 32 + wid * 2;
    const float4* xr0 = (const float4*)(x + (size_t)row0 * 1024);
    const float4* xr1 = (const float4*)(x + (size_t)(row0 + 1) * 1024);
    float4 v[2][4];
#pragma unroll
    for (int j = 0; j < 4; ++j) v[0][j] = xr0[lane + j * 64];
#pragma unroll
    for (int j = 0; j < 4; ++j) v[1][j] = xr1[lane + j * 64];
    float ss0 = 0.f, ss1 = 0.f;
#pragma unroll
    for (int j = 0; j < 4; ++j) {
      ss0 += v[0][j].x * v[0][j].x + v[0][j].y * v[0][j].y +
             v[0][j].z * v[0][j].z + v[0][j].w * v[0][j].w;
      ss1 += v[1][j].x * v[1][j].x + v[1][j].y * v[1][j].y +
             v[1][j].z * v[1][j].z + v[1][j].w * v[1][j].w;
    }
#pragma unroll
    for (int m = 1; m < 64; m <<= 1) {
      ss0 += __shfl_xor(ss0, m);
      ss1 += __shfl_xor(ss1, m);
    }
    float rn0 = 1.f / fmaxf(sqrtf(ss0), 1e-8f);
    float rn1 = 1.f / fmaxf(sqrtf(ss1), 1e-8f);
    if (lane == 0) {
      rnorm[row0] = rn0;
      rnorm[row0 + 1] = rn1;
    }
    float4 sacc[4];
#pragma unroll
    for (int j = 0; j < 4; ++j) {
      ushort4 h0, h1;
      h0.x = f2bf(v[0][j].x); h0.y = f2bf(v[0][j].y);
      h0.z = f2bf(v[0][j].z); h0.w = f2bf(v[0][j].w);
      h1.x = f2bf(v[1][j].x); h1.y = f2bf(v[1][j].y);
      h1.z = f2bf(v[1][j].z); h1.w = f2bf(v[1][j].w);
      ((ushort4*)(xbf + (size_t)row0 * 1024))[lane + j * 64] = h0;
      ((ushort4*)(xbf + (size_t)(row0 + 1) * 1024))[lane + j * 64] = h1;
      sacc[j].x = v[0][j].x * rn0 + v[1][j].x * rn1;
      sacc[j].y = v[0][j].y * rn0 + v[1][j].y * rn1;
      sacc[j].z = v[0][j].z * rn0 + v[1][j].z * rn1;
      sacc[j].w = v[0][j].w * rn0 + v[1][j].w * rn1;
    }
#pragma unroll
    for (int j = 0; j < 4; ++j) ((float4*)sblk[wid])[j * 64 + lane] = sacc[j];
    __syncthreads();
    float acc = 0.f;
#pragma unroll
    for (int w = 0; w < 16; ++w) acc += sblk[w][tid];
    sp[(size_t)b * 1024 + tid] = acc;  // plain store, no RMW
  }

  {
    float (*tile)[65] = (float(*)[65])(sm + 65536);
#pragma unroll
    for (int i = 0; i < 4; ++i) tile[i * 16 + ty][tx] = wreg[i];
    __syncthreads();
#pragma unroll
    for (int i = 0; i < 4; ++i) {
      int ct = i * 16 + ty;
      Wt[(size_t)(c0 + ct) * 1024 + (k0 + tx)] = f2bf(tile[tx][ct]);
    }
  }
}

// ---------------------------------------------------------------------------
// K2: reduce sp[256][1024] -> s[1024]. (R15-identical)
// ---------------------------------------------------------------------------
__global__ __launch_bounds__(256) void k2_sred(const float* __restrict__ sp,
                                               float* __restrict__ s) {
  __shared__ float red[4][64];
  int t = threadIdx.x;
  int dd = t & 63;
  int g = t >> 6;
  int d = blockIdx.x * 64 + dd;
  float acc = 0.f;
#pragma unroll 8
  for (int b = g * 64; b < g * 64 + 64; ++b) acc += sp[(size_t)b * 1024 + d];
  red[g][dd] = acc;
  __syncthreads();
  if (g == 0) s[d] = red[0][dd] + red[1][dd] + red[2][dd] + red[3][dd];
}

// ---------------------------------------------------------------------------
// K3: m97-replica GEMM + softmax partials (R15-identical). 128x128 tile,
// 256 thr, dbuf 64KB -> 2 blocks/CU, XOR-swizzle, XCD-aligned cb=b>>6.
// ---------------------------------------------------------------------------
__global__ __launch_bounds__(256) void k3_gemm(const unsigned short* __restrict__ xbf,
                                               const unsigned short* __restrict__ wt,
                                               const float* __restrict__ bias,
                                               float* __restrict__ pm,
                                               float* __restrict__ pz,
                                               float* __restrict__ ps) {
  __shared__ __align__(16) char lds[65536];

  int tid = threadIdx.x;
  int lane = tid & 63;
  int wid = tid >> 6;
  int wc = wid & 1;
  int wr = wid >> 1;
  int cb = blockIdx.x >> 6;
  int rb = blockIdx.x & 63;
  int C0 = cb * 128;
  int R0 = rb * 128;

  float bv[4][4];
#pragma unroll
  for (int mf = 0; mf < 4; ++mf)
#pragma unroll
    for (int q = 0; q < 4; ++q) {
      int cls_g = C0 + wc * 64 + mf * 16 + (lane >> 4) * 4 + q;
      bv[mf][q] = (cls_g < 1000) ? bias[cls_g] : -1e30f;
    }
  f32x4 acc[4][4];
#pragma unroll
  for (int mf = 0; mf < 4; ++mf)
#pragma unroll
    for (int nf = 0; nf < 4; ++nf)
#pragma unroll
      for (int q = 0; q < 4; ++q) acc[mf][nf][q] = bv[mf][q];

  const char* gA = (const char*)(wt + (size_t)C0 * 1024);
  const char* gB = (const char*)(xbf + (size_t)R0 * 1024);
  int grow = (tid >> 3) & 7;
  int gswz = ((tid & 7) ^ grow) << 4;

  auto stage = [&](int kt, int bb) {
    char* lA = lds + bb * 32768;
    char* lB = lA + 16384;
#pragma unroll
    for (int i = 0; i < 4; ++i) {
      size_t row = i * 32 + (tid >> 3);
      gload_lds16(gA + row * 2048 + kt * 128 + gswz, lA + i * 4096 + tid * 16);
    }
#pragma unroll
    for (int i = 0; i < 4; ++i) {
      size_t row = i * 32 + (tid >> 3);
      gload_lds16(gB + row * 2048 + kt * 128 + gswz, lB + i * 4096 + tid * 16);
    }
  };

  int rsw = (lane & 7) << 4;
  int kcol = (lane >> 4) * 16;

  stage(0, 0);
  __syncthreads();
  int cur = 0;
  for (int t = 0; t < 16; ++t) {
    if (t < 15) stage(t + 1, cur ^ 1);
    const char* A = lds + cur * 32768;
    const char* B = A + 16384;
    bf16x8 a[4][2], bb[4][2];
#pragma unroll
    for (int mf = 0; mf < 4; ++mf)
#pragma unroll
      for (int ks = 0; ks < 2; ++ks)
        a[mf][ks] = *(const bf16x8*)(A + (wc * 64 + mf * 16 + (lane & 15)) * 128 +
                                     ((ks * 64 + kcol) ^ rsw));
#pragma unroll
    for (int nf = 0; nf < 4; ++nf)
#pragma unroll
      for (int ks = 0; ks < 2; ++ks)
        bb[nf][ks] = *(const bf16x8*)(B + (wr * 64 + nf * 16 + (lane & 15)) * 128 +
                                      ((ks * 64 + kcol) ^ rsw));
    __builtin_amdgcn_s_setprio(1);
#pragma unroll
    for (int ks = 0; ks < 2; ++ks)
#pragma unroll
      for (int mf = 0; mf < 4; ++mf)
#pragma unroll
        for (int nf = 0; nf < 4; ++nf)
          acc[mf][nf] = __builtin_amdgcn_mfma_f32_16x16x32_bf16(a[mf][ks], bb[nf][ks],
                                                                acc[mf][nf], 0, 0, 0);
    __builtin_amdgcn_s_setprio(0);
    __syncthreads();
    cur ^= 1;
  }

  float* mm = (float*)lds;
  float* zz = mm + 256;
  float* sv = zz + 256;
#pragma unroll
  for (int nf = 0; nf < 4; ++nf) {
    float m1 = -1e30f;
#pragma unroll
    for (int mf = 0; mf < 4; ++mf)
#pragma unroll
      for (int q = 0; q < 4; ++q) m1 = fmaxf(m1, acc[mf][nf][q]);
    m1 = fmaxf(m1, __shfl_xor(m1, 16));
    m1 = fmaxf(m1, __shfl_xor(m1, 32));
    float z1 = 0.f, s1 = 0.f;
#pragma unroll
    for (int mf = 0; mf < 4; ++mf)
#pragma unroll
      for (int q = 0; q < 4; ++q) {
        float tt = acc[mf][nf][q] - m1;
        float e = expf(tt);
        z1 += e;
        s1 += e * tt;
      }
    z1 += __shfl_xor(z1, 16); z1 += __shfl_xor(z1, 32);
    s1 += __shfl_xor(s1, 16); s1 += __shfl_xor(s1, 32);
    if (lane < 16) {
      int r = wr * 64 + nf * 16 + lane;
      mm[wc * 128 + r] = m1;
      zz[wc * 128 + r] = z1;
      sv[wc * 128 + r] = s1;
    }
  }
  __syncthreads();
  if (tid < 128) {
    float m0 = mm[tid], mA = mm[128 + tid];
    float z0 = zz[tid], zA = zz[128 + tid];
    float s0 = sv[tid], sA = sv[128 + tid];
    float M = fmaxf(m0, mA);
    float e0 = expf(m0 - M), e1 = expf(mA - M);
    float Z = z0 * e0 + zA * e1;
    float S = e0 * (s0 + (m0 - M) * z0) + e1 * (sA + (mA - M) * zA);
    size_t o = (size_t)cb * 8192 + R0 + tid;
    pm[o] = M;
    pz[o] = Z;
    ps[o] = S;
  }
}

// ---------------------------------------------------------------------------
// K4: parallel merge (R15-identical).
// ---------------------------------------------------------------------------
__global__ __launch_bounds__(256) void k4_final(const unsigned short* __restrict__ xbf,
                                                const float* __restrict__ s,
                                                const float* __restrict__ rnorm,
                                                const float* __restrict__ pm,
                                                const float* __restrict__ pz,
                                                const float* __restrict__ ps,
                                                float* __restrict__ out) {
  int tid = threadIdx.x;
  int wid = tid >> 6, lane = tid & 63;
  int row = blockIdx.x * 4 + wid;
  const bf16x8* xr = (const bf16x8*)(xbf + (size_t)row * 1024);
  const float4* s4 = (const float4*)s;
  float dot = 0.f;
#pragma unroll
  for (int j = 0; j < 2; ++j) {
    bf16x8 v = xr[lane + j * 64];
    float4 sa = s4[(lane + j * 64) * 2];
    float4 sb = s4[(lane + j * 64) * 2 + 1];
    dot += bf2f((unsigned short)v[0]) * sa.x + bf2f((unsigned short)v[1]) * sa.y +
           bf2f((unsigned short)v[2]) * sa.z + bf2f((unsigned short)v[3]) * sa.w +
           bf2f((unsigned short)v[4]) * sb.x + bf2f((unsigned short)v[5]) * sb.y +
           bf2f((unsigned short)v[6]) * sb.z + bf2f((unsigned short)v[7]) * sb.w;
  }
#pragma unroll
  for (int m = 1; m < 64; m <<= 1) dot += __shfl_xor(dot, m);
  if (lane == 0) {
    float mv[8], zv[8], svv[8];
    float M = -1e30f;
#pragma unroll
    for (int c = 0; c < 8; ++c) {
      mv[c] = pm[(size_t)c * 8192 + row];
      zv[c] = pz[(size_t)c * 8192 + row];
      svv[c] = ps[(size_t)c * 8192 + row];
      M = fmaxf(M, mv[c]);
    }
    float Z = 0.f, S = 0.f;
#pragma unroll
    for (int c = 0; c < 8; ++c) {
      float e = expf(mv[c] - M);
      Z += zv[c] * e;
      S += e * (svv[c] + (mv[c] - M) * zv[c]);
    }
    float loss = S / Z - logf(Z);
    out[row] = loss * dot * rnorm[row] * (1.f / 8192.f);
  }
}

// ---------------------------------------------------------------------------
extern "C" void kernel_launch(void* const* d_in, const int* in_sizes, int n_in,
                              void* d_out, int out_size, void* d_ws, size_t ws_size,
                              hipStream_t stream) {
  (void)in_sizes; (void)n_in; (void)out_size; (void)ws_size;
  const float* x = (const float*)d_in[0];
  const float* W = (const float*)d_in[1];
  const float* b = (const float*)d_in[2];
  float* out = (float*)d_out;
  char* ws = (char*)d_ws;

  unsigned short* Wt = (unsigned short*)(ws + 0);           // 2 MiB
  unsigned short* xbf = (unsigned short*)(ws + 2097152);    // 16 MiB
  float* rnorm = (float*)(ws + 18874368);                   // 32 KiB
  float* s = (float*)(ws + 18907136);                       // 4 KiB
  float* sp = (float*)(ws + 18915328);                      // aliases pm region
  float* pm = (float*)(ws + 18915328);                      // 256 KiB
  float* pz = (float*)(ws + 18915328 + 262144);
  float* ps = (float*)(ws + 18915328 + 524288);

  // k01 launched TWICE (duration probe; idempotent). Delta vs R15 = k01 time.
  k01_prep<<<256, 1024, 0, stream>>>(W, Wt, x, xbf, rnorm, sp);
  k01_prep<<<256, 1024, 0, stream>>>(W, Wt, x, xbf, rnorm, sp);
  k2_sred<<<16, 256, 0, stream>>>(sp, s);
  k3_gemm<<<512, 256, 0, stream>>>(xbf, Wt, b, pm, pz, ps);
  k4_final<<<2048, 256, 0, stream>>>(xbf, s, rnorm, pm, pz, ps, out);
}

// Round 17
// 54.144 us; speedup vs baseline: 1.1543x; 1.1543x over previous
//
#include <hip/hip_runtime.h>
#include <hip/hip_bf16.h>
#include <cstdint>
#include <cstddef>

typedef __attribute__((ext_vector_type(8))) short bf16x8;
typedef __attribute__((ext_vector_type(4))) float f32x4;

__device__ __forceinline__ unsigned short f2bf(float f) {
  union { float f; unsigned u; } v; v.f = f;
  unsigned r = v.u + 0x7FFFu + ((v.u >> 16) & 1u);
  return (unsigned short)(r >> 16);
}

__device__ __forceinline__ float bf2f(unsigned short h) {
  union { float f; unsigned u; } c; c.u = ((unsigned)h) << 16;
  return c.f;
}

__device__ __forceinline__ void gload_lds16(const void* g, void* l) {
  __builtin_amdgcn_global_load_lds(
      (const __attribute__((address_space(1))) unsigned int*)g,
      (__attribute__((address_space(3))) unsigned int*)l, 16, 0, 0);
}

// ---------------------------------------------------------------------------
// K01: 256 blocks x 1024 thr. x-phase identical to R15 (measured: ~10us, at
// BW floor). W output changed: Wt is written FRAG-MAJOR -- one 1KB record per
// 16x32 MFMA A-fragment, lane l's 16B at record*1024 + l*16 holding
// A[cls=cf*16+(l&15)][k: kf*32+(l>>4)*8 .. +8). k3 then loads A-frags as
// single coalesced global reads (no LDS staging for A at all).
// Frag record id = (cls/16)*32 + (k/32).
// ---------------------------------------------------------------------------
__global__ __launch_bounds__(1024) void k01_prep(const float* __restrict__ W,
                                                 unsigned short* __restrict__ wtf,
                                                 const float* __restrict__ x,
                                                 unsigned short* __restrict__ xbf,
                                                 float* __restrict__ rnorm,
                                                 float* __restrict__ sp) {
  __shared__ __align__(16) char sm[83968];  // sblk 64KB @0 | tile2 18432B @65536
  int tid = threadIdx.x;
  int b = blockIdx.x;
  int lane = tid & 63;
  int wid = tid >> 6;  // 0..15

  int k0 = (b & 15) * 64;
  int c0 = (b >> 4) * 64;
  int tx = tid & 63;
  int ty = tid >> 6;
  float wreg[4];
#pragma unroll
  for (int i = 0; i < 4; ++i) {
    int c = c0 + tx;
    wreg[i] = (c < 1000) ? W[(size_t)(k0 + i * 16 + ty) * 1000 + c] : 0.f;
  }

  // x phase (R15-identical)
  {
    float (*sblk)[1024] = (float(*)[1024])sm;
    int row0 = b * 32 + wid * 2;
    const float4* xr0 = (const float4*)(x + (size_t)row0 * 1024);
    const float4* xr1 = (const float4*)(x + (size_t)(row0 + 1) * 1024);
    float4 v[2][4];
#pragma unroll
    for (int j = 0; j < 4; ++j) v[0][j] = xr0[lane + j * 64];
#pragma unroll
    for (int j = 0; j < 4; ++j) v[1][j] = xr1[lane + j * 64];
    float ss0 = 0.f, ss1 = 0.f;
#pragma unroll
    for (int j = 0; j < 4; ++j) {
      ss0 += v[0][j].x * v[0][j].x + v[0][j].y * v[0][j].y +
             v[0][j].z * v[0][j].z + v[0][j].w * v[0][j].w;
      ss1 += v[1][j].x * v[1][j].x + v[1][j].y * v[1][j].y +
             v[1][j].z * v[1][j].z + v[1][j].w * v[1][j].w;
    }
#pragma unroll
    for (int m = 1; m < 64; m <<= 1) {
      ss0 += __shfl_xor(ss0, m);
      ss1 += __shfl_xor(ss1, m);
    }
    float rn0 = 1.f / fmaxf(sqrtf(ss0), 1e-8f);
    float rn1 = 1.f / fmaxf(sqrtf(ss1), 1e-8f);
    if (lane == 0) {
      rnorm[row0] = rn0;
      rnorm[row0 + 1] = rn1;
    }
    float4 sacc[4];
#pragma unroll
    for (int j = 0; j < 4; ++j) {
      ushort4 h0, h1;
      h0.x = f2bf(v[0][j].x); h0.y = f2bf(v[0][j].y);
      h0.z = f2bf(v[0][j].z); h0.w = f2bf(v[0][j].w);
      h1.x = f2bf(v[1][j].x); h1.y = f2bf(v[1][j].y);
      h1.z = f2bf(v[1][j].z); h1.w = f2bf(v[1][j].w);
      ((ushort4*)(xbf + (size_t)row0 * 1024))[lane + j * 64] = h0;
      ((ushort4*)(xbf + (size_t)(row0 + 1) * 1024))[lane + j * 64] = h1;
      sacc[j].x = v[0][j].x * rn0 + v[1][j].x * rn1;
      sacc[j].y = v[0][j].y * rn0 + v[1][j].y * rn1;
      sacc[j].z = v[0][j].z * rn0 + v[1][j].z * rn1;
      sacc[j].w = v[0][j].w * rn0 + v[1][j].w * rn1;
    }
#pragma unroll
    for (int j = 0; j < 4; ++j) ((float4*)sblk[wid])[j * 64 + lane] = sacc[j];
    __syncthreads();
    float acc = 0.f;
#pragma unroll
    for (int w = 0; w < 16; ++w) acc += sblk[w][tid];
    sp[(size_t)b * 1024 + tid] = acc;
  }

  // W frag-major output: tile2[cls][k] (64x72 f32, padded), then 8 frags.
  {
    float (*tile2)[72] = (float(*)[72])(sm + 65536);
#pragma unroll
    for (int i = 0; i < 4; ++i) tile2[tx][i * 16 + ty] = wreg[i];
    __syncthreads();
    if (tid < 512) {
      int fi = tid >> 6;   // 0..7: cf = fi>>1 (0..3), kf = fi&1 (0..1)
      int l = tid & 63;
      int cf = fi >> 1;
      int kf = fi & 1;
      int r2 = cf * 16 + (l & 15);
      int c2 = kf * 32 + (l >> 4) * 8;
      float4 va = *(const float4*)&tile2[r2][c2];
      float4 vb = *(const float4*)&tile2[r2][c2 + 4];
      uint4 o;
      o.x = (unsigned)f2bf(va.x) | ((unsigned)f2bf(va.y) << 16);
      o.y = (unsigned)f2bf(va.z) | ((unsigned)f2bf(va.w) << 16);
      o.z = (unsigned)f2bf(vb.x) | ((unsigned)f2bf(vb.y) << 16);
      o.w = (unsigned)f2bf(vb.z) | ((unsigned)f2bf(vb.w) << 16);
      size_t fg = (size_t)(c0 / 16 + cf) * 32 + (k0 / 32 + kf);
      *(uint4*)((char*)wtf + fg * 1024 + (size_t)l * 16) = o;
    }
  }
}

// ---------------------------------------------------------------------------
// K2: reduce sp[256][1024] -> s[1024]. (R15-identical)
// ---------------------------------------------------------------------------
__global__ __launch_bounds__(256) void k2_sred(const float* __restrict__ sp,
                                               float* __restrict__ s) {
  __shared__ float red[4][64];
  int t = threadIdx.x;
  int dd = t & 63;
  int g = t >> 6;
  int d = blockIdx.x * 64 + dd;
  float acc = 0.f;
#pragma unroll 8
  for (int b = g * 64; b < g * 64 + 64; ++b) acc += sp[(size_t)b * 1024 + d];
  red[g][dd] = acc;
  __syncthreads();
  if (g == 0) s[d] = red[0][dd] + red[1][dd] + red[2][dd] + red[3][dd];
}

// ---------------------------------------------------------------------------
// K3: GEMM + softmax partials. A-FRAGS DIRECT FROM GLOBAL (frag-major wtf,
// coalesced 1KB loads, L2-resident) -- no A LDS staging, no A ds_reads.
// LDS holds only B (16KB/step, dbuf 32KB -> 3+ blocks/CU). Per-block-step
// LDS traffic halved 96KB -> 48KB (R16 diagnosis: k3 is LDS-BW-bound).
// B path byte-identical to R15 (swizzle proven). 128x128 tile, 256 thr,
// XCD-aligned cb=b>>6, rb=b&63.
// ---------------------------------------------------------------------------
__global__ __launch_bounds__(256) void k3_gemm(const unsigned short* __restrict__ xbf,
                                               const unsigned short* __restrict__ wtf,
                                               const float* __restrict__ bias,
                                               float* __restrict__ pm,
                                               float* __restrict__ pz,
                                               float* __restrict__ ps) {
  __shared__ __align__(16) char lds[32768];  // B dbuf 2 x 16KB

  int tid = threadIdx.x;
  int lane = tid & 63;
  int wid = tid >> 6;  // 0..3
  int wc = wid & 1;    // cls half
  int wr = wid >> 1;   // row half
  int cb = blockIdx.x >> 6;  // 0..7
  int rb = blockIdx.x & 63;  // 0..63 -> XCD = rb % 8
  int C0 = cb * 128;
  int R0 = rb * 128;

  float bv[4][4];
#pragma unroll
  for (int mf = 0; mf < 4; ++mf)
#pragma unroll
    for (int q = 0; q < 4; ++q) {
      int cls_g = C0 + wc * 64 + mf * 16 + (lane >> 4) * 4 + q;
      bv[mf][q] = (cls_g < 1000) ? bias[cls_g] : -1e30f;
    }
  f32x4 acc[4][4];
#pragma unroll
  for (int mf = 0; mf < 4; ++mf)
#pragma unroll
    for (int nf = 0; nf < 4; ++nf)
#pragma unroll
      for (int q = 0; q < 4; ++q) acc[mf][nf][q] = bv[mf][q];

  const char* gB = (const char*)(xbf + (size_t)R0 * 1024);
  int grow = (tid >> 3) & 7;
  int gswz = ((tid & 7) ^ grow) << 4;

  // stage B tile kt into buf bb (4 rounds x 4KB), linear dest + pre-swizzled src
  auto stageB = [&](int kt, int bb) {
    char* lB = lds + bb * 16384;
#pragma unroll
    for (int i = 0; i < 4; ++i) {
      size_t row = i * 32 + (tid >> 3);
      gload_lds16(gB + row * 2048 + kt * 128 + gswz, lB + i * 4096 + tid * 16);
    }
  };

  // A frag base: wave (wc) owns cls-frags cb*8 + wc*4 + mf, k-frag = t*2 + ks
  const char* gAf = (const char*)wtf +
                    ((size_t)(cb * 8 + wc * 4) * 32) * 1024 + (size_t)lane * 16;

  int rsw = (lane & 7) << 4;
  int kcol = (lane >> 4) * 16;

  stageB(0, 0);
  __syncthreads();
  int cur = 0;
  for (int t = 0; t < 16; ++t) {
    if (t < 15) stageB(t + 1, cur ^ 1);
    // A frags: direct coalesced global loads (L2-hot, frag-major)
    bf16x8 a[4][2], bb[4][2];
#pragma unroll
    for (int mf = 0; mf < 4; ++mf)
#pragma unroll
      for (int ks = 0; ks < 2; ++ks)
        a[mf][ks] = *(const bf16x8*)(gAf + (size_t)(mf * 32 + t * 2 + ks) * 1024);
    const char* B = lds + cur * 16384;
#pragma unroll
    for (int nf = 0; nf < 4; ++nf)
#pragma unroll
      for (int ks = 0; ks < 2; ++ks)
        bb[nf][ks] = *(const bf16x8*)(B + (wr * 64 + nf * 16 + (lane & 15)) * 128 +
                                      ((ks * 64 + kcol) ^ rsw));
    __builtin_amdgcn_s_setprio(1);
#pragma unroll
    for (int ks = 0; ks < 2; ++ks)
#pragma unroll
      for (int mf = 0; mf < 4; ++mf)
#pragma unroll
        for (int nf = 0; nf < 4; ++nf)
          acc[mf][nf] = __builtin_amdgcn_mfma_f32_16x16x32_bf16(a[mf][ks], bb[nf][ks],
                                                                acc[mf][nf], 0, 0, 0);
    __builtin_amdgcn_s_setprio(0);
    __syncthreads();
    cur ^= 1;
  }

  // epilogue (R15-identical)
  float* mm = (float*)lds;
  float* zz = mm + 256;
  float* sv = zz + 256;
#pragma unroll
  for (int nf = 0; nf < 4; ++nf) {
    float m1 = -1e30f;
#pragma unroll
    for (int mf = 0; mf < 4; ++mf)
#pragma unroll
      for (int q = 0; q < 4; ++q) m1 = fmaxf(m1, acc[mf][nf][q]);
    m1 = fmaxf(m1, __shfl_xor(m1, 16));
    m1 = fmaxf(m1, __shfl_xor(m1, 32));
    float z1 = 0.f, s1 = 0.f;
#pragma unroll
    for (int mf = 0; mf < 4; ++mf)
#pragma unroll
      for (int q = 0; q < 4; ++q) {
        float tt = acc[mf][nf][q] - m1;
        float e = expf(tt);
        z1 += e;
        s1 += e * tt;
      }
    z1 += __shfl_xor(z1, 16); z1 += __shfl_xor(z1, 32);
    s1 += __shfl_xor(s1, 16); s1 += __shfl_xor(s1, 32);
    if (lane < 16) {
      int r = wr * 64 + nf * 16 + lane;
      mm[wc * 128 + r] = m1;
      zz[wc * 128 + r] = z1;
      sv[wc * 128 + r] = s1;
    }
  }
  __syncthreads();
  if (tid < 128) {
    float m0 = mm[tid], mA = mm[128 + tid];
    float z0 = zz[tid], zA = zz[128 + tid];
    float s0 = sv[tid], sA = sv[128 + tid];
    float M = fmaxf(m0, mA);
    float e0 = expf(m0 - M), e1 = expf(mA - M);
    float Z = z0 * e0 + zA * e1;
    float S = e0 * (s0 + (m0 - M) * z0) + e1 * (sA + (mA - M) * zA);
    size_t o = (size_t)cb * 8192 + R0 + tid;
    pm[o] = M;
    pz[o] = Z;
    ps[o] = S;
  }
}

// ---------------------------------------------------------------------------
// K4: parallel merge (R15-identical).
// ---------------------------------------------------------------------------
__global__ __launch_bounds__(256) void k4_final(const unsigned short* __restrict__ xbf,
                                                const float* __restrict__ s,
                                                const float* __restrict__ rnorm,
                                                const float* __restrict__ pm,
                                                const float* __restrict__ pz,
                                                const float* __restrict__ ps,
                                                float* __restrict__ out) {
  int tid = threadIdx.x;
  int wid = tid >> 6, lane = tid & 63;
  int row = blockIdx.x * 4 + wid;
  const bf16x8* xr = (const bf16x8*)(xbf + (size_t)row * 1024);
  const float4* s4 = (const float4*)s;
  float dot = 0.f;
#pragma unroll
  for (int j = 0; j < 2; ++j) {
    bf16x8 v = xr[lane + j * 64];
    float4 sa = s4[(lane + j * 64) * 2];
    float4 sb = s4[(lane + j * 64) * 2 + 1];
    dot += bf2f((unsigned short)v[0]) * sa.x + bf2f((unsigned short)v[1]) * sa.y +
           bf2f((unsigned short)v[2]) * sa.z + bf2f((unsigned short)v[3]) * sa.w +
           bf2f((unsigned short)v[4]) * sb.x + bf2f((unsigned short)v[5]) * sb.y +
           bf2f((unsigned short)v[6]) * sb.z + bf2f((unsigned short)v[7]) * sb.w;
  }
#pragma unroll
  for (int m = 1; m < 64; m <<= 1) dot += __shfl_xor(dot, m);
  if (lane == 0) {
    float mv[8], zv[8], svv[8];
    float M = -1e30f;
#pragma unroll
    for (int c = 0; c < 8; ++c) {
      mv[c] = pm[(size_t)c * 8192 + row];
      zv[c] = pz[(size_t)c * 8192 + row];
      svv[c] = ps[(size_t)c * 8192 + row];
      M = fmaxf(M, mv[c]);
    }
    float Z = 0.f, S = 0.f;
#pragma unroll
    for (int c = 0; c < 8; ++c) {
      float e = expf(mv[c] - M);
      Z += zv[c] * e;
      S += e * (svv[c] + (mv[c] - M) * zv[c]);
    }
    float loss = S / Z - logf(Z);
    out[row] = loss * dot * rnorm[row] * (1.f / 8192.f);
  }
}

// ---------------------------------------------------------------------------
extern "C" void kernel_launch(void* const* d_in, const int* in_sizes, int n_in,
                              void* d_out, int out_size, void* d_ws, size_t ws_size,
                              hipStream_t stream) {
  (void)in_sizes; (void)n_in; (void)out_size; (void)ws_size;
  const float* x = (const float*)d_in[0];
  const float* W = (const float*)d_in[1];
  const float* b = (const float*)d_in[2];
  float* out = (float*)d_out;
  char* ws = (char*)d_ws;

  unsigned short* wtf = (unsigned short*)(ws + 0);          // 2 MiB, frag-major
  unsigned short* xbf = (unsigned short*)(ws + 2097152);    // 16 MiB
  float* rnorm = (float*)(ws + 18874368);                   // 32 KiB
  float* s = (float*)(ws + 18907136);                       // 4 KiB
  float* sp = (float*)(ws + 18915328);                      // aliases pm region
  float* pm = (float*)(ws + 18915328);                      // 256 KiB
  float* pz = (float*)(ws + 18915328 + 262144);
  float* ps = (float*)(ws + 18915328 + 524288);

  k01_prep<<<256, 1024, 0, stream>>>(W, wtf, x, xbf, rnorm, sp);
  k2_sred<<<16, 256, 0, stream>>>(sp, s);
  k3_gemm<<<512, 256, 0, stream>>>(xbf, wtf, b, pm, pz, ps);
  k4_final<<<2048, 256, 0, stream>>>(xbf, s, rnorm, pm, pz, ps, out);
}

// Round 18
// 48.948 us; speedup vs baseline: 1.2768x; 1.1062x over previous
//
#include <hip/hip_runtime.h>
#include <hip/hip_bf16.h>
#include <cstdint>
#include <cstddef>

typedef __attribute__((ext_vector_type(8))) short bf16x8;
typedef __attribute__((ext_vector_type(4))) float f32x4;

__device__ __forceinline__ unsigned short f2bf(float f) {
  union { float f; unsigned u; } v; v.f = f;
  unsigned r = v.u + 0x7FFFu + ((v.u >> 16) & 1u);
  return (unsigned short)(r >> 16);
}

__device__ __forceinline__ float bf2f(unsigned short h) {
  union { float f; unsigned u; } c; c.u = ((unsigned)h) << 16;
  return c.f;
}

__device__ __forceinline__ void gload_lds16(const void* g, void* l) {
  __builtin_amdgcn_global_load_lds(
      (const __attribute__((address_space(1))) unsigned int*)g,
      (__attribute__((address_space(3))) unsigned int*)l, 16, 0, 0);
}

// ---------------------------------------------------------------------------
// K01 (R15-proven): 256 blocks x 1024 thr. W loads hoisted to regs; x-phase
// (measured 9.9us, at BW floor): rnorm, x->bf16, per-block s-partial via
// plain stores to sp. Wt written row-major [1024cls][1024k]; rows 1001+ are
// never read (cls>1000 masked in k3); row 1000 is written by k2 (= bf16(s)).
// ---------------------------------------------------------------------------
__global__ __launch_bounds__(1024) void k01_prep(const float* __restrict__ W,
                                                 unsigned short* __restrict__ Wt,
                                                 const float* __restrict__ x,
                                                 unsigned short* __restrict__ xbf,
                                                 float* __restrict__ rnorm,
                                                 float* __restrict__ sp) {
  __shared__ __align__(16) char sm[82176];
  int tid = threadIdx.x;
  int b = blockIdx.x;
  int lane = tid & 63;
  int wid = tid >> 6;  // 0..15

  int k0 = (b & 15) * 64;
  int c0 = (b >> 4) * 64;
  int tx = tid & 63;
  int ty = tid >> 6;
  float wreg[4];
#pragma unroll
  for (int i = 0; i < 4; ++i) {
    int c = c0 + tx;
    wreg[i] = (c < 1000) ? W[(size_t)(k0 + i * 16 + ty) * 1000 + c] : 0.f;
  }

  {
    float (*sblk)[1024] = (float(*)[1024])sm;
    int row0 = b * 32 + wid * 2;
    const float4* xr0 = (const float4*)(x + (size_t)row0 * 1024);
    const float4* xr1 = (const float4*)(x + (size_t)(row0 + 1) * 1024);
    float4 v[2][4];
#pragma unroll
    for (int j = 0; j < 4; ++j) v[0][j] = xr0[lane + j * 64];
#pragma unroll
    for (int j = 0; j < 4; ++j) v[1][j] = xr1[lane + j * 64];
    float ss0 = 0.f, ss1 = 0.f;
#pragma unroll
    for (int j = 0; j < 4; ++j) {
      ss0 += v[0][j].x * v[0][j].x + v[0][j].y * v[0][j].y +
             v[0][j].z * v[0][j].z + v[0][j].w * v[0][j].w;
      ss1 += v[1][j].x * v[1][j].x + v[1][j].y * v[1][j].y +
             v[1][j].z * v[1][j].z + v[1][j].w * v[1][j].w;
    }
#pragma unroll
    for (int m = 1; m < 64; m <<= 1) {
      ss0 += __shfl_xor(ss0, m);
      ss1 += __shfl_xor(ss1, m);
    }
    float rn0 = 1.f / fmaxf(sqrtf(ss0), 1e-8f);
    float rn1 = 1.f / fmaxf(sqrtf(ss1), 1e-8f);
    if (lane == 0) {
      rnorm[row0] = rn0;
      rnorm[row0 + 1] = rn1;
    }
    float4 sacc[4];
#pragma unroll
    for (int j = 0; j < 4; ++j) {
      ushort4 h0, h1;
      h0.x = f2bf(v[0][j].x); h0.y = f2bf(v[0][j].y);
      h0.z = f2bf(v[0][j].z); h0.w = f2bf(v[0][j].w);
      h1.x = f2bf(v[1][j].x); h1.y = f2bf(v[1][j].y);
      h1.z = f2bf(v[1][j].z); h1.w = f2bf(v[1][j].w);
      ((ushort4*)(xbf + (size_t)row0 * 1024))[lane + j * 64] = h0;
      ((ushort4*)(xbf + (size_t)(row0 + 1) * 1024))[lane + j * 64] = h1;
      sacc[j].x = v[0][j].x * rn0 + v[1][j].x * rn1;
      sacc[j].y = v[0][j].y * rn0 + v[1][j].y * rn1;
      sacc[j].z = v[0][j].z * rn0 + v[1][j].z * rn1;
      sacc[j].w = v[0][j].w * rn0 + v[1][j].w * rn1;
    }
#pragma unroll
    for (int j = 0; j < 4; ++j) ((float4*)sblk[wid])[j * 64 + lane] = sacc[j];
    __syncthreads();
    float acc = 0.f;
#pragma unroll
    for (int w = 0; w < 16; ++w) acc += sblk[w][tid];
    sp[(size_t)b * 1024 + tid] = acc;
  }

  {
    float (*tile)[65] = (float(*)[65])(sm + 65536);
#pragma unroll
    for (int i = 0; i < 4; ++i) tile[i * 16 + ty][tx] = wreg[i];
    __syncthreads();
#pragma unroll
    for (int i = 0; i < 4; ++i) {
      int ct = i * 16 + ty;
      Wt[(size_t)(c0 + ct) * 1024 + (k0 + tx)] = f2bf(tile[tx][ct]);
    }
  }
}

// ---------------------------------------------------------------------------
// K2: reduce sp[256][1024] -> s[1024], AND write bf16(s) into Wt row 1000
// (class-1000 trick, R5/R8-proven: the GEMM then computes dot(x_row, s)
// for free as logit 1000).
// ---------------------------------------------------------------------------
__global__ __launch_bounds__(256) void k2_sred(const float* __restrict__ sp,
                                               float* __restrict__ s,
                                               unsigned short* __restrict__ Wt) {
  __shared__ float red[4][64];
  int t = threadIdx.x;
  int dd = t & 63;
  int g = t >> 6;
  int d = blockIdx.x * 64 + dd;
  float acc = 0.f;
#pragma unroll 8
  for (int b = g * 64; b < g * 64 + 64; ++b) acc += sp[(size_t)b * 1024 + d];
  red[g][dd] = acc;
  __syncthreads();
  if (g == 0) {
    float sv = red[0][dd] + red[1][dd] + red[2][dd] + red[3][dd];
    s[d] = sv;
    Wt[(size_t)1000 * 1024 + d] = f2bf(sv);
  }
}

// ---------------------------------------------------------------------------
// K3 (R15-proven structure): 128x128 tile, 256 thr (4 waves, wave=64x64),
// BK=64, dbuf 64KB -> 2 blocks/CU, XOR-swizzle (inverse on global src),
// XCD-aligned cb=b>>6 / rb=b&63. Class-1000 = dot(x_row, s): bias 0,
// extracted to pd post-loop (cb7/wc1/mf2/lanegrp2/q0 per C/D map), masked
// to -1e30 before the softmax stats. cls > 1000 masked as before.
// ---------------------------------------------------------------------------
__global__ __launch_bounds__(256) void k3_gemm(const unsigned short* __restrict__ xbf,
                                               const unsigned short* __restrict__ wt,
                                               const float* __restrict__ bias,
                                               float* __restrict__ pm,
                                               float* __restrict__ pz,
                                               float* __restrict__ ps,
                                               float* __restrict__ pd) {
  __shared__ __align__(16) char lds[65536];

  int tid = threadIdx.x;
  int lane = tid & 63;
  int wid = tid >> 6;
  int wc = wid & 1;
  int wr = wid >> 1;
  int cb = blockIdx.x >> 6;
  int rb = blockIdx.x & 63;
  int C0 = cb * 128;
  int R0 = rb * 128;

  float bv[4][4];
#pragma unroll
  for (int mf = 0; mf < 4; ++mf)
#pragma unroll
    for (int q = 0; q < 4; ++q) {
      int cls_g = C0 + wc * 64 + mf * 16 + (lane >> 4) * 4 + q;
      bv[mf][q] = (cls_g < 1000) ? bias[cls_g] : ((cls_g == 1000) ? 0.f : -1e30f);
    }
  f32x4 acc[4][4];
#pragma unroll
  for (int mf = 0; mf < 4; ++mf)
#pragma unroll
    for (int nf = 0; nf < 4; ++nf)
#pragma unroll
      for (int q = 0; q < 4; ++q) acc[mf][nf][q] = bv[mf][q];

  const char* gA = (const char*)(wt + (size_t)C0 * 1024);
  const char* gB = (const char*)(xbf + (size_t)R0 * 1024);
  int grow = (tid >> 3) & 7;
  int gswz = ((tid & 7) ^ grow) << 4;

  auto stage = [&](int kt, int bb) {
    char* lA = lds + bb * 32768;
    char* lB = lA + 16384;
#pragma unroll
    for (int i = 0; i < 4; ++i) {
      size_t row = i * 32 + (tid >> 3);
      gload_lds16(gA + row * 2048 + kt * 128 + gswz, lA + i * 4096 + tid * 16);
    }
#pragma unroll
    for (int i = 0; i < 4; ++i) {
      size_t row = i * 32 + (tid >> 3);
      gload_lds16(gB + row * 2048 + kt * 128 + gswz, lB + i * 4096 + tid * 16);
    }
  };

  int rsw = (lane & 7) << 4;
  int kcol = (lane >> 4) * 16;

  stage(0, 0);
  __syncthreads();
  int cur = 0;
  for (int t = 0; t < 16; ++t) {
    if (t < 15) stage(t + 1, cur ^ 1);
    const char* A = lds + cur * 32768;
    const char* B = A + 16384;
    bf16x8 a[4][2], bb[4][2];
#pragma unroll
    for (int mf = 0; mf < 4; ++mf)
#pragma unroll
      for (int ks = 0; ks < 2; ++ks)
        a[mf][ks] = *(const bf16x8*)(A + (wc * 64 + mf * 16 + (lane & 15)) * 128 +
                                     ((ks * 64 + kcol) ^ rsw));
#pragma unroll
    for (int nf = 0; nf < 4; ++nf)
#pragma unroll
      for (int ks = 0; ks < 2; ++ks)
        bb[nf][ks] = *(const bf16x8*)(B + (wr * 64 + nf * 16 + (lane & 15)) * 128 +
                                      ((ks * 64 + kcol) ^ rsw));
    __builtin_amdgcn_s_setprio(1);
#pragma unroll
    for (int ks = 0; ks < 2; ++ks)
#pragma unroll
      for (int mf = 0; mf < 4; ++mf)
#pragma unroll
        for (int nf = 0; nf < 4; ++nf)
          acc[mf][nf] = __builtin_amdgcn_mfma_f32_16x16x32_bf16(a[mf][ks], bb[nf][ks],
                                                                acc[mf][nf], 0, 0, 0);
    __builtin_amdgcn_s_setprio(0);
    __syncthreads();
    cur ^= 1;
  }

  // class-1000 dot extraction (cls 1000 = C0(896) + wc*64(64) + mf*16(32) +
  // lanegrp*4(8) + q(0) -> cb7, wc1, mf2, lane>>4==2, q==0).
  if (cb == 7 && wc == 1 && ((lane >> 4) == 2)) {
#pragma unroll
    for (int nf = 0; nf < 4; ++nf) {
      int r = wr * 64 + nf * 16 + (lane & 15);
      pd[(size_t)rb * 128 + r] = acc[2][nf][0];
      acc[2][nf][0] = -1e30f;
    }
  }

  float* mm = (float*)lds;
  float* zz = mm + 256;
  float* sv = zz + 256;
  __syncthreads();
#pragma unroll
  for (int nf = 0; nf < 4; ++nf) {
    float m1 = -1e30f;
#pragma unroll
    for (int mf = 0; mf < 4; ++mf)
#pragma unroll
      for (int q = 0; q < 4; ++q) m1 = fmaxf(m1, acc[mf][nf][q]);
    m1 = fmaxf(m1, __shfl_xor(m1, 16));
    m1 = fmaxf(m1, __shfl_xor(m1, 32));
    float z1 = 0.f, s1 = 0.f;
#pragma unroll
    for (int mf = 0; mf < 4; ++mf)
#pragma unroll
      for (int q = 0; q < 4; ++q) {
        float tt = acc[mf][nf][q] - m1;
        float e = expf(tt);
        z1 += e;
        s1 += e * tt;
      }
    z1 += __shfl_xor(z1, 16); z1 += __shfl_xor(z1, 32);
    s1 += __shfl_xor(s1, 16); s1 += __shfl_xor(s1, 32);
    if (lane < 16) {
      int r = wr * 64 + nf * 16 + lane;
      mm[wc * 128 + r] = m1;
      zz[wc * 128 + r] = z1;
      sv[wc * 128 + r] = s1;
    }
  }
  __syncthreads();
  if (tid < 128) {
    float m0 = mm[tid], mA = mm[128 + tid];
    float z0 = zz[tid], zA = zz[128 + tid];
    float s0 = sv[tid], sA = sv[128 + tid];
    float M = fmaxf(m0, mA);
    float e0 = expf(m0 - M), e1 = expf(mA - M);
    float Z = z0 * e0 + zA * e1;
    float S = e0 * (s0 + (m0 - M) * z0) + e1 * (sA + (mA - M) * zA);
    size_t o = (size_t)cb * 8192 + R0 + tid;
    pm[o] = M;
    pz[o] = Z;
    ps[o] = S;
  }
}

// ---------------------------------------------------------------------------
// K4 slim: 32 blocks x 256 thr, one THREAD per row. Merges 8 partials +
// pd-dot + rnorm -> out. Reads ~820KB total (no xbf re-read).
// ---------------------------------------------------------------------------
__global__ __launch_bounds__(256) void k4_final(const float* __restrict__ rnorm,
                                                const float* __restrict__ pm,
                                                const float* __restrict__ pz,
                                                const float* __restrict__ ps,
                                                const float* __restrict__ pd,
                                                float* __restrict__ out) {
  int row = blockIdx.x * 256 + threadIdx.x;
  float mv[8], zv[8], svv[8];
  float M = -1e30f;
#pragma unroll
  for (int c = 0; c < 8; ++c) {
    mv[c] = pm[(size_t)c * 8192 + row];
    zv[c] = pz[(size_t)c * 8192 + row];
    svv[c] = ps[(size_t)c * 8192 + row];
    M = fmaxf(M, mv[c]);
  }
  float Z = 0.f, S = 0.f;
#pragma unroll
  for (int c = 0; c < 8; ++c) {
    float e = expf(mv[c] - M);
    Z += zv[c] * e;
    S += e * (svv[c] + (mv[c] - M) * zv[c]);
  }
  float loss = S / Z - logf(Z);
  out[row] = loss * pd[row] * rnorm[row] * (1.f / 8192.f);
}

// ---------------------------------------------------------------------------
extern "C" void kernel_launch(void* const* d_in, const int* in_sizes, int n_in,
                              void* d_out, int out_size, void* d_ws, size_t ws_size,
                              hipStream_t stream) {
  (void)in_sizes; (void)n_in; (void)out_size; (void)ws_size;
  const float* x = (const float*)d_in[0];
  const float* W = (const float*)d_in[1];
  const float* b = (const float*)d_in[2];
  float* out = (float*)d_out;
  char* ws = (char*)d_ws;

  unsigned short* Wt = (unsigned short*)(ws + 0);           // 2 MiB (row 1000 = s)
  unsigned short* xbf = (unsigned short*)(ws + 2097152);    // 16 MiB
  float* rnorm = (float*)(ws + 18874368);                   // 32 KiB
  float* s = (float*)(ws + 18907136);                       // 4 KiB
  float* sp = (float*)(ws + 18915328);                      // 1 MiB, aliases pm
  float* pm = (float*)(ws + 18915328);                      // 256 KiB
  float* pz = (float*)(ws + 18915328 + 262144);
  float* ps = (float*)(ws + 18915328 + 524288);
  float* pd = (float*)(ws + 18915328 + 786432);             // 32 KiB

  k01_prep<<<256, 1024, 0, stream>>>(W, Wt, x, xbf, rnorm, sp);
  k2_sred<<<16, 256, 0, stream>>>(sp, s, Wt);
  k3_gemm<<<512, 256, 0, stream>>>(xbf, Wt, b, pm, pz, ps, pd);
  k4_final<<<32, 256, 0, stream>>>(rnorm, pm, pz, ps, pd, out);
}

// Round 19
// 46.263 us; speedup vs baseline: 1.3510x; 1.0581x over previous
//
#include <hip/hip_runtime.h>
#include <hip/hip_bf16.h>
#include <cstdint>
#include <cstddef>

typedef __attribute__((ext_vector_type(8))) short bf16x8;
typedef __attribute__((ext_vector_type(4))) float f32x4;

__device__ __forceinline__ unsigned short f2bf(float f) {
  union { float f; unsigned u; } v; v.f = f;
  unsigned r = v.u + 0x7FFFu + ((v.u >> 16) & 1u);
  return (unsigned short)(r >> 16);
}

__device__ __forceinline__ float bf2f(unsigned short h) {
  union { float f; unsigned u; } c; c.u = ((unsigned)h) << 16;
  return c.f;
}

__device__ __forceinline__ void gload_lds16(const void* g, void* l) {
  __builtin_amdgcn_global_load_lds(
      (const __attribute__((address_space(1))) unsigned int*)g,
      (__attribute__((address_space(3))) unsigned int*)l, 16, 0, 0);
}

// ---------------------------------------------------------------------------
// K01 (R18-identical, measured ~10us = BW floor): 256 blocks x 1024 thr.
// W hoisted to regs; x-phase: rnorm, x->bf16, s-partials via plain stores.
// Wt row-major; row 1000 reserved (written by k2 = bf16(s)).
// ---------------------------------------------------------------------------
__global__ __launch_bounds__(1024) void k01_prep(const float* __restrict__ W,
                                                 unsigned short* __restrict__ Wt,
                                                 const float* __restrict__ x,
                                                 unsigned short* __restrict__ xbf,
                                                 float* __restrict__ rnorm,
                                                 float* __restrict__ sp) {
  __shared__ __align__(16) char sm[82176];
  int tid = threadIdx.x;
  int b = blockIdx.x;
  int lane = tid & 63;
  int wid = tid >> 6;  // 0..15

  int k0 = (b & 15) * 64;
  int c0 = (b >> 4) * 64;
  int tx = tid & 63;
  int ty = tid >> 6;
  float wreg[4];
#pragma unroll
  for (int i = 0; i < 4; ++i) {
    int c = c0 + tx;
    wreg[i] = (c < 1000) ? W[(size_t)(k0 + i * 16 + ty) * 1000 + c] : 0.f;
  }

  {
    float (*sblk)[1024] = (float(*)[1024])sm;
    int row0 = b * 32 + wid * 2;
    const float4* xr0 = (const float4*)(x + (size_t)row0 * 1024);
    const float4* xr1 = (const float4*)(x + (size_t)(row0 + 1) * 1024);
    float4 v[2][4];
#pragma unroll
    for (int j = 0; j < 4; ++j) v[0][j] = xr0[lane + j * 64];
#pragma unroll
    for (int j = 0; j < 4; ++j) v[1][j] = xr1[lane + j * 64];
    float ss0 = 0.f, ss1 = 0.f;
#pragma unroll
    for (int j = 0; j < 4; ++j) {
      ss0 += v[0][j].x * v[0][j].x + v[0][j].y * v[0][j].y +
             v[0][j].z * v[0][j].z + v[0][j].w * v[0][j].w;
      ss1 += v[1][j].x * v[1][j].x + v[1][j].y * v[1][j].y +
             v[1][j].z * v[1][j].z + v[1][j].w * v[1][j].w;
    }
#pragma unroll
    for (int m = 1; m < 64; m <<= 1) {
      ss0 += __shfl_xor(ss0, m);
      ss1 += __shfl_xor(ss1, m);
    }
    float rn0 = 1.f / fmaxf(sqrtf(ss0), 1e-8f);
    float rn1 = 1.f / fmaxf(sqrtf(ss1), 1e-8f);
    if (lane == 0) {
      rnorm[row0] = rn0;
      rnorm[row0 + 1] = rn1;
    }
    float4 sacc[4];
#pragma unroll
    for (int j = 0; j < 4; ++j) {
      ushort4 h0, h1;
      h0.x = f2bf(v[0][j].x); h0.y = f2bf(v[0][j].y);
      h0.z = f2bf(v[0][j].z); h0.w = f2bf(v[0][j].w);
      h1.x = f2bf(v[1][j].x); h1.y = f2bf(v[1][j].y);
      h1.z = f2bf(v[1][j].z); h1.w = f2bf(v[1][j].w);
      ((ushort4*)(xbf + (size_t)row0 * 1024))[lane + j * 64] = h0;
      ((ushort4*)(xbf + (size_t)(row0 + 1) * 1024))[lane + j * 64] = h1;
      sacc[j].x = v[0][j].x * rn0 + v[1][j].x * rn1;
      sacc[j].y = v[0][j].y * rn0 + v[1][j].y * rn1;
      sacc[j].z = v[0][j].z * rn0 + v[1][j].z * rn1;
      sacc[j].w = v[0][j].w * rn0 + v[1][j].w * rn1;
    }
#pragma unroll
    for (int j = 0; j < 4; ++j) ((float4*)sblk[wid])[j * 64 + lane] = sacc[j];
    __syncthreads();
    float acc = 0.f;
#pragma unroll
    for (int w = 0; w < 16; ++w) acc += sblk[w][tid];
    sp[(size_t)b * 1024 + tid] = acc;
  }

  {
    float (*tile)[65] = (float(*)[65])(sm + 65536);
#pragma unroll
    for (int i = 0; i < 4; ++i) tile[i * 16 + ty][tx] = wreg[i];
    __syncthreads();
#pragma unroll
    for (int i = 0; i < 4; ++i) {
      int ct = i * 16 + ty;
      Wt[(size_t)(c0 + ct) * 1024 + (k0 + tx)] = f2bf(tile[tx][ct]);
    }
  }
}

// ---------------------------------------------------------------------------
// K2 (R18-identical): reduce sp -> s, write bf16(s) into Wt row 1000.
// ---------------------------------------------------------------------------
__global__ __launch_bounds__(256) void k2_sred(const float* __restrict__ sp,
                                               float* __restrict__ s,
                                               unsigned short* __restrict__ Wt) {
  __shared__ float red[4][64];
  int t = threadIdx.x;
  int dd = t & 63;
  int g = t >> 6;
  int d = blockIdx.x * 64 + dd;
  float acc = 0.f;
#pragma unroll 8
  for (int b = g * 64; b < g * 64 + 64; ++b) acc += sp[(size_t)b * 1024 + d];
  red[g][dd] = acc;
  __syncthreads();
  if (g == 0) {
    float sv = red[0][dd] + red[1][dd] + red[2][dd] + red[3][dd];
    s[d] = sv;
    Wt[(size_t)1000 * 1024 + d] = f2bf(sv);
  }
}

// ---------------------------------------------------------------------------
// K3 = R12's tri-buffer kernel (the variant R9 DIRECTLY measured at 24.8us
// warm) + R8's proven class-1000 extraction. 128 cls x 256 rows, 512 thr
// (8 waves 2c x 4r), BK=64, tri-buffer 147KB, depth-2 prefetch, counted
// vmcnt(6), peeled tile-15 behind vmcnt(0), XOR-swizzle, XCD-aligned
// cb=b>>5 / rb=b&31. Plain partial stores; slim k4 merges.
// ---------------------------------------------------------------------------
#define LDSBUF 49152

__global__ __launch_bounds__(512) void k3_gemm(const unsigned short* __restrict__ xbf,
                                               const unsigned short* __restrict__ wt,
                                               const float* __restrict__ bias,
                                               float* __restrict__ pm,
                                               float* __restrict__ pz,
                                               float* __restrict__ ps,
                                               float* __restrict__ pd) {
  __shared__ __align__(16) char lds[147456];

  int tid = threadIdx.x;
  int lane = tid & 63;
  int wid = tid >> 6;
  int wc = wid & 1;
  int wr = wid >> 1;
  int cb = blockIdx.x >> 5;   // cls chunk: same-rb blocks share an XCD
  int rb = blockIdx.x & 31;   // row block -> XCD = rb % 8
  int C0 = cb * 128;
  int R0 = rb * 256;

  float bv[4][4];
#pragma unroll
  for (int mf = 0; mf < 4; ++mf)
#pragma unroll
    for (int q = 0; q < 4; ++q) {
      int cls_g = C0 + wc * 64 + mf * 16 + (lane >> 4) * 4 + q;
      bv[mf][q] = (cls_g < 1000) ? bias[cls_g] : ((cls_g == 1000) ? 0.f : -1e30f);
    }
  f32x4 acc[4][4];
#pragma unroll
  for (int mf = 0; mf < 4; ++mf)
#pragma unroll
    for (int nf = 0; nf < 4; ++nf)
#pragma unroll
      for (int q = 0; q < 4; ++q) acc[mf][nf][q] = bv[mf][q];

  const char* gA = (const char*)(wt + (size_t)C0 * 1024);
  const char* gB = (const char*)(xbf + (size_t)R0 * 1024);
  int grow = lane >> 3;
  int gswz = ((lane & 7) ^ grow) << 4;

#define STA(kt, b, r)                                                          \
  gload_lds16(gA + (size_t)((r) * 64 + wid * 8 + grow) * 2048 + (kt) * 128 +   \
                  gswz,                                                        \
              lds + (b) * LDSBUF + (r) * 8192 + wid * 1024)
#define STB(kt, b, r)                                                          \
  gload_lds16(gB + (size_t)((r) * 64 + wid * 8 + grow) * 2048 + (kt) * 128 +   \
                  gswz,                                                        \
              lds + (b) * LDSBUF + 16384 + (r) * 8192 + wid * 1024)

  STA(0, 0, 0); STA(0, 0, 1); STB(0, 0, 0); STB(0, 0, 1); STB(0, 0, 2); STB(0, 0, 3);
  STA(1, 1, 0); STA(1, 1, 1); STB(1, 1, 0); STB(1, 1, 1); STB(1, 1, 2); STB(1, 1, 3);

  int rsw = (lane & 7) << 4;
  int kcol = (lane >> 4) * 16;

  auto ktile = [&](const char* A, const char* B, int nt, int nb, bool pf) {
    if (pf) { STA(nt, nb, 0); STA(nt, nb, 1); }
    bf16x8 a[4][2];
#pragma unroll
    for (int mf = 0; mf < 4; ++mf)
#pragma unroll
      for (int ks = 0; ks < 2; ++ks)
        a[mf][ks] = *(const bf16x8*)(A + (wc * 64 + mf * 16 + (lane & 15)) * 128 +
                                     ((ks * 64 + kcol) ^ rsw));
    {
      bf16x8 b0[2];
#pragma unroll
      for (int ks = 0; ks < 2; ++ks)
        b0[ks] = *(const bf16x8*)(B + (wr * 64 + 0 * 16 + (lane & 15)) * 128 +
                                  ((ks * 64 + kcol) ^ rsw));
      __builtin_amdgcn_s_setprio(1);
#pragma unroll
      for (int ks = 0; ks < 2; ++ks)
#pragma unroll
        for (int mf = 0; mf < 4; ++mf)
          acc[mf][0] = __builtin_amdgcn_mfma_f32_16x16x32_bf16(a[mf][ks], b0[ks],
                                                               acc[mf][0], 0, 0, 0);
      __builtin_amdgcn_s_setprio(0);
    }
    if (pf) { STB(nt, nb, 0); STB(nt, nb, 1); }
    {
      bf16x8 b1[2];
#pragma unroll
      for (int ks = 0; ks < 2; ++ks)
        b1[ks] = *(const bf16x8*)(B + (wr * 64 + 1 * 16 + (lane & 15)) * 128 +
                                  ((ks * 64 + kcol) ^ rsw));
      __builtin_amdgcn_s_setprio(1);
#pragma unroll
      for (int ks = 0; ks < 2; ++ks)
#pragma unroll
        for (int mf = 0; mf < 4; ++mf)
          acc[mf][1] = __builtin_amdgcn_mfma_f32_16x16x32_bf16(a[mf][ks], b1[ks],
                                                               acc[mf][1], 0, 0, 0);
      __builtin_amdgcn_s_setprio(0);
    }
    if (pf) { STB(nt, nb, 2); STB(nt, nb, 3); }
    {
      bf16x8 b2[2];
#pragma unroll
      for (int ks = 0; ks < 2; ++ks)
        b2[ks] = *(const bf16x8*)(B + (wr * 64 + 2 * 16 + (lane & 15)) * 128 +
                                  ((ks * 64 + kcol) ^ rsw));
      __builtin_amdgcn_s_setprio(1);
#pragma unroll
      for (int ks = 0; ks < 2; ++ks)
#pragma unroll
        for (int mf = 0; mf < 4; ++mf)
          acc[mf][2] = __builtin_amdgcn_mfma_f32_16x16x32_bf16(a[mf][ks], b2[ks],
                                                               acc[mf][2], 0, 0, 0);
      __builtin_amdgcn_s_setprio(0);
    }
    {
      bf16x8 b3[2];
#pragma unroll
      for (int ks = 0; ks < 2; ++ks)
        b3[ks] = *(const bf16x8*)(B + (wr * 64 + 3 * 16 + (lane & 15)) * 128 +
                                  ((ks * 64 + kcol) ^ rsw));
      __builtin_amdgcn_s_setprio(1);
#pragma unroll
      for (int ks = 0; ks < 2; ++ks)
#pragma unroll
        for (int mf = 0; mf < 4; ++mf)
          acc[mf][3] = __builtin_amdgcn_mfma_f32_16x16x32_bf16(a[mf][ks], b3[ks],
                                                               acc[mf][3], 0, 0, 0);
      __builtin_amdgcn_s_setprio(0);
    }
  };

  for (int t = 0; t < 15; ++t) {
    asm volatile("s_waitcnt vmcnt(6)" ::: "memory");
    __builtin_amdgcn_s_barrier();
    asm volatile("" ::: "memory");
    const char* A = lds + (t % 3) * LDSBUF;
    ktile(A, A + 16384, t + 2, (t + 2) % 3, t < 14);
  }
  asm volatile("s_waitcnt vmcnt(0)" ::: "memory");
  __builtin_amdgcn_s_barrier();
  asm volatile("" ::: "memory");
  {
    const char* A = lds + (15 % 3) * LDSBUF;
    ktile(A, A + 16384, 0, 0, false);
  }

  // class-1000 dot extraction (cls1000 = 896 + 64 + 32 + 8 + 0 -> cb7, wc1,
  // mf2, lane>>4==2, q==0). pd[row] = dot(x_row, s).
  if (cb == 7 && wc == 1 && ((lane >> 4) == 2)) {
#pragma unroll
    for (int nf = 0; nf < 4; ++nf) {
      int r = wr * 64 + nf * 16 + (lane & 15);
      pd[(size_t)rb * 256 + r] = acc[2][nf][0];
      acc[2][nf][0] = -1e30f;
    }
  }

  __syncthreads();
  float* mm = (float*)lds;
  float* zz = mm + 512;
  float* sv = zz + 512;
#pragma unroll
  for (int nf = 0; nf < 4; ++nf) {
    float m1 = -1e30f;
#pragma unroll
    for (int mf = 0; mf < 4; ++mf)
#pragma unroll
      for (int q = 0; q < 4; ++q) m1 = fmaxf(m1, acc[mf][nf][q]);
    m1 = fmaxf(m1, __shfl_xor(m1, 16));
    m1 = fmaxf(m1, __shfl_xor(m1, 32));
    float z1 = 0.f, s1 = 0.f;
#pragma unroll
    for (int mf = 0; mf < 4; ++mf)
#pragma unroll
      for (int q = 0; q < 4; ++q) {
        float tt = acc[mf][nf][q] - m1;
        float e = expf(tt);
        z1 += e;
        s1 += e * tt;
      }
    z1 += __shfl_xor(z1, 16); z1 += __shfl_xor(z1, 32);
    s1 += __shfl_xor(s1, 16); s1 += __shfl_xor(s1, 32);
    if (lane < 16) {
      int r = wr * 64 + nf * 16 + lane;
      mm[wc * 256 + r] = m1;
      zz[wc * 256 + r] = z1;
      sv[wc * 256 + r] = s1;
    }
  }
  __syncthreads();
  if (tid < 256) {
    float m0 = mm[tid], mA = mm[256 + tid];
    float z0 = zz[tid], zA = zz[256 + tid];
    float s0 = sv[tid], sA = sv[256 + tid];
    float M = fmaxf(m0, mA);
    float e0 = expf(m0 - M), e1 = expf(mA - M);
    float Z = z0 * e0 + zA * e1;
    float S = e0 * (s0 + (m0 - M) * z0) + e1 * (sA + (mA - M) * zA);
    size_t o = (size_t)cb * 8192 + R0 + tid;
    pm[o] = M;
    pz[o] = Z;
    ps[o] = S;
  }
}

// ---------------------------------------------------------------------------
// K4 slim (R18-identical): 32 blocks x 256 thr, one thread per row.
// ---------------------------------------------------------------------------
__global__ __launch_bounds__(256) void k4_final(const float* __restrict__ rnorm,
                                                const float* __restrict__ pm,
                                                const float* __restrict__ pz,
                                                const float* __restrict__ ps,
                                                const float* __restrict__ pd,
                                                float* __restrict__ out) {
  int row = blockIdx.x * 256 + threadIdx.x;
  float mv[8], zv[8], svv[8];
  float M = -1e30f;
#pragma unroll
  for (int c = 0; c < 8; ++c) {
    mv[c] = pm[(size_t)c * 8192 + row];
    zv[c] = pz[(size_t)c * 8192 + row];
    svv[c] = ps[(size_t)c * 8192 + row];
    M = fmaxf(M, mv[c]);
  }
  float Z = 0.f, S = 0.f;
#pragma unroll
  for (int c = 0; c < 8; ++c) {
    float e = expf(mv[c] - M);
    Z += zv[c] * e;
    S += e * (svv[c] + (mv[c] - M) * zv[c]);
  }
  float loss = S / Z - logf(Z);
  out[row] = loss * pd[row] * rnorm[row] * (1.f / 8192.f);
}

// ---------------------------------------------------------------------------
extern "C" void kernel_launch(void* const* d_in, const int* in_sizes, int n_in,
                              void* d_out, int out_size, void* d_ws, size_t ws_size,
                              hipStream_t stream) {
  (void)in_sizes; (void)n_in; (void)out_size; (void)ws_size;
  const float* x = (const float*)d_in[0];
  const float* W = (const float*)d_in[1];
  const float* b = (const float*)d_in[2];
  float* out = (float*)d_out;
  char* ws = (char*)d_ws;

  unsigned short* Wt = (unsigned short*)(ws + 0);           // 2 MiB (row 1000 = s)
  unsigned short* xbf = (unsigned short*)(ws + 2097152);    // 16 MiB
  float* rnorm = (float*)(ws + 18874368);                   // 32 KiB
  float* s = (float*)(ws + 18907136);                       // 4 KiB
  float* sp = (float*)(ws + 18915328);                      // 1 MiB, aliases pm
  float* pm = (float*)(ws + 18915328);                      // 256 KiB
  float* pz = (float*)(ws + 18915328 + 262144);
  float* ps = (float*)(ws + 18915328 + 524288);
  float* pd = (float*)(ws + 18915328 + 786432);             // 32 KiB

  k01_prep<<<256, 1024, 0, stream>>>(W, Wt, x, xbf, rnorm, sp);
  k2_sred<<<16, 256, 0, stream>>>(sp, s, Wt);
  k3_gemm<<<256, 512, 0, stream>>>(xbf, Wt, b, pm, pz, ps, pd);
  k4_final<<<32, 256, 0, stream>>>(rnorm, pm, pz, ps, pd, out);
}